// Round 1
// baseline (145.050 us; speedup 1.0000x reference)
//
#include <hip/hip_runtime.h>
#include <hip/hip_bf16.h>

#define N 4096
#define D 256
#define BM 64
#define BN 64
#define BK 16
#define LDST 68          // LDS row stride (floats): 64 + 4 pad -> bank-friendly, 16B aligned
#define MARGIN 0.3f
#define FLT_MAX_BITS 0x7F7FFFFF

// Kernel 1: per-row squared norms + init atomic targets.
// One wave (64 lanes) per row; 4 rows per 256-thread block.
__global__ __launch_bounds__(256) void norms_init_kernel(
        const float* __restrict__ feat,
        float* __restrict__ xx,
        int* __restrict__ apbits,
        int* __restrict__ anbits) {
    int row  = blockIdx.x * 4 + (threadIdx.x >> 6);
    int lane = threadIdx.x & 63;
    float4 v = *(const float4*)(feat + row * D + lane * 4);
    float s = v.x * v.x + v.y * v.y + v.z * v.z + v.w * v.w;
    #pragma unroll
    for (int off = 32; off >= 1; off >>= 1) s += __shfl_xor(s, off);
    if (lane == 0) {
        xx[row]     = s;
        apbits[row] = 0;             // 0.0f  (safe: diagonal positive always exists)
        anbits[row] = FLT_MAX_BITS;  // FLT_MAX
    }
}

// Kernel 2: fused distance tile + masked row max/min.
// Grid: (N/BM) x 16 strips. Block 256 threads, per-thread 4x4 micro-tile.
__global__ __launch_bounds__(256) void dist_minmax_kernel(
        const float* __restrict__ feat,
        const int* __restrict__ labels,
        const float* __restrict__ xx,
        int* __restrict__ apbits,
        int* __restrict__ anbits) {
    __shared__ float As[BK][LDST];
    __shared__ float Bs[BK][LDST];

    const int rowBase  = blockIdx.x * BM;
    const int colStart = blockIdx.y * 256;   // 16 strips * 256 cols

    const int tid = threadIdx.x;
    const int tx  = tid & 15;     // column group 0..15
    const int ty  = tid >> 4;     // row group 0..15

    // staging: one float4 per thread per matrix per K-chunk
    const int srow = tid >> 2;         // 0..63
    const int sk4  = (tid & 3) * 4;    // 0,4,8,12

    float xr[4]; int lr[4];
    float pmax[4], nmin[4];
    #pragma unroll
    for (int r = 0; r < 4; ++r) {
        int row = rowBase + ty * 4 + r;
        xr[r]   = xx[row];
        lr[r]   = labels[row];
        pmax[r] = 0.0f;
        nmin[r] = 3.402823466e+38f;
    }

    for (int ct = 0; ct < 4; ++ct) {
        const int colBase = colStart + ct * BN;

        float xc[4]; int lc[4];
        #pragma unroll
        for (int c = 0; c < 4; ++c) {
            xc[c] = xx[colBase + tx * 4 + c];
            lc[c] = labels[colBase + tx * 4 + c];
        }

        float acc[4][4];
        #pragma unroll
        for (int r = 0; r < 4; ++r)
            #pragma unroll
            for (int c = 0; c < 4; ++c) acc[r][c] = 0.0f;

        for (int kt = 0; kt < D; kt += BK) {
            __syncthreads();
            float4 av = *(const float4*)(feat + (rowBase + srow) * D + kt + sk4);
            float4 bv = *(const float4*)(feat + (colBase + srow) * D + kt + sk4);
            As[sk4 + 0][srow] = av.x; As[sk4 + 1][srow] = av.y;
            As[sk4 + 2][srow] = av.z; As[sk4 + 3][srow] = av.w;
            Bs[sk4 + 0][srow] = bv.x; Bs[sk4 + 1][srow] = bv.y;
            Bs[sk4 + 2][srow] = bv.z; Bs[sk4 + 3][srow] = bv.w;
            __syncthreads();

            #pragma unroll
            for (int k = 0; k < BK; ++k) {
                float4 a = *(const float4*)&As[k][ty * 4];
                float4 b = *(const float4*)&Bs[k][tx * 4];
                acc[0][0] += a.x * b.x; acc[0][1] += a.x * b.y;
                acc[0][2] += a.x * b.z; acc[0][3] += a.x * b.w;
                acc[1][0] += a.y * b.x; acc[1][1] += a.y * b.y;
                acc[1][2] += a.y * b.z; acc[1][3] += a.y * b.w;
                acc[2][0] += a.z * b.x; acc[2][1] += a.z * b.y;
                acc[2][2] += a.z * b.z; acc[2][3] += a.z * b.w;
                acc[3][0] += a.w * b.x; acc[3][1] += a.w * b.y;
                acc[3][2] += a.w * b.z; acc[3][3] += a.w * b.w;
            }
        }

        // epilogue: distances + masked running max/min
        #pragma unroll
        for (int r = 0; r < 4; ++r) {
            #pragma unroll
            for (int c = 0; c < 4; ++c) {
                float d2 = xr[r] + xc[c] - 2.0f * acc[r][c];
                float d  = sqrtf(fmaxf(d2, 1e-12f));
                bool pos = (lr[r] == lc[c]);
                pmax[r] = pos ? fmaxf(pmax[r], d) : pmax[r];
                nmin[r] = pos ? nmin[r] : fminf(nmin[r], d);
            }
        }
    }

    // reduce over the 16 column groups (lanes differing in bits 0..3)
    #pragma unroll
    for (int r = 0; r < 4; ++r) {
        #pragma unroll
        for (int off = 1; off <= 8; off <<= 1) {
            pmax[r] = fmaxf(pmax[r], __shfl_xor(pmax[r], off));
            nmin[r] = fminf(nmin[r], __shfl_xor(nmin[r], off));
        }
    }
    if (tx == 0) {
        #pragma unroll
        for (int r = 0; r < 4; ++r) {
            int row = rowBase + ty * 4 + r;
            atomicMax(&apbits[row], __float_as_int(pmax[r]));  // dist >= 0 -> int order ok
            atomicMin(&anbits[row], __float_as_int(nmin[r]));
        }
    }
}

// Kernel 3: final margin-ranking loss reduction (single block).
__global__ __launch_bounds__(256) void loss_kernel(
        const int* __restrict__ apbits,
        const int* __restrict__ anbits,
        float* __restrict__ out) {
    __shared__ float ssum[4], scnt[4];
    int tid = threadIdx.x;
    float sum = 0.0f, cnt = 0.0f;
    for (int i = tid; i < N; i += 256) {
        float ap = __int_as_float(apbits[i]);
        float an = __int_as_float(anbits[i]);
        bool valid = (ap < 1.0e6f) && (an > 0.0f);
        float per = fmaxf(MARGIN + ap - an, 0.0f);
        if (valid) { sum += per; cnt += 1.0f; }
    }
    #pragma unroll
    for (int off = 32; off >= 1; off >>= 1) {
        sum += __shfl_xor(sum, off);
        cnt += __shfl_xor(cnt, off);
    }
    int wv = tid >> 6;
    if ((tid & 63) == 0) { ssum[wv] = sum; scnt[wv] = cnt; }
    __syncthreads();
    if (tid == 0) {
        float S = ssum[0] + ssum[1] + ssum[2] + ssum[3];
        float C = scnt[0] + scnt[1] + scnt[2] + scnt[3];
        out[0] = (C > 0.0f) ? S / fmaxf(C, 1.0f) : 0.0f;
    }
}

extern "C" void kernel_launch(void* const* d_in, const int* in_sizes, int n_in,
                              void* d_out, int out_size, void* d_ws, size_t ws_size,
                              hipStream_t stream) {
    const float* feat  = (const float*)d_in[0];
    const int* labels  = (const int*)d_in[1];
    float* xx   = (float*)d_ws;
    int* apbits = (int*)((char*)d_ws + (size_t)N * 4);
    int* anbits = (int*)((char*)d_ws + (size_t)N * 8);
    float* out  = (float*)d_out;

    norms_init_kernel<<<N / 4, 256, 0, stream>>>(feat, xx, apbits, anbits);
    dim3 grid(N / BM, 16);
    dist_minmax_kernel<<<grid, 256, 0, stream>>>(feat, labels, xx, apbits, anbits);
    loss_kernel<<<1, 256, 0, stream>>>(apbits, anbits, out);
}

// Round 2
// 53.428 us; speedup vs baseline: 2.7149x; 2.7149x over previous
//
#include <hip/hip_runtime.h>
#include <hip/hip_bf16.h>

#define N 4096
#define D 256
#define MARGIN 0.3f
#define FLT_MAX_BITS 0x7F7FFFFF

typedef __attribute__((ext_vector_type(8))) short short8;
typedef __attribute__((ext_vector_type(4))) float f32x4;
typedef const __attribute__((address_space(1))) unsigned char g1_t;
typedef __attribute__((address_space(3))) unsigned char l3_t;

__device__ __forceinline__ ushort f2bf(float f) {
    unsigned u = __float_as_uint(f);
    unsigned r = (u + 0x7fffu + ((u >> 16) & 1u)) >> 16;   // RNE
    return (ushort)r;
}
__device__ __forceinline__ float bf2f(ushort h) {
    return __uint_as_float(((unsigned)h) << 16);
}

// Kernel 1: per-row squared norms, bf16 hi/lo split, init atomic targets.
__global__ __launch_bounds__(256) void prep_kernel(
        const float* __restrict__ feat,
        float* __restrict__ xx,
        int* __restrict__ apbits,
        int* __restrict__ anbits,
        ushort* __restrict__ hi,
        ushort* __restrict__ lo) {
    int row  = blockIdx.x * 4 + (threadIdx.x >> 6);
    int lane = threadIdx.x & 63;
    float4 v = *(const float4*)(feat + row * D + lane * 4);
    ushort h0 = f2bf(v.x), h1 = f2bf(v.y), h2 = f2bf(v.z), h3 = f2bf(v.w);
    ushort l0 = f2bf(v.x - bf2f(h0)), l1 = f2bf(v.y - bf2f(h1));
    ushort l2 = f2bf(v.z - bf2f(h2)), l3 = f2bf(v.w - bf2f(h3));
    *(ushort4*)(hi + row * D + lane * 4) = make_ushort4(h0, h1, h2, h3);
    *(ushort4*)(lo + row * D + lane * 4) = make_ushort4(l0, l1, l2, l3);
    float s = v.x * v.x + v.y * v.y + v.z * v.z + v.w * v.w;
    #pragma unroll
    for (int off = 32; off >= 1; off >>= 1) s += __shfl_xor(s, off);
    if (lane == 0) {
        xx[row]     = s;
        apbits[row] = 0;             // running max of pos d^2 (>= 0)
        anbits[row] = FLT_MAX_BITS;  // running min of neg d^2
    }
}

// Kernel 2: 128x128 bf16-MFMA tile (split hi/lo, 3 passes: hh + hl + lh),
// fused distance epilogue with masked row max/min in d^2 domain.
__global__ __launch_bounds__(256, 2) void dist_mfma_kernel(
        const ushort* __restrict__ hi, const ushort* __restrict__ lo,
        const int* __restrict__ labels, const float* __restrict__ xx,
        int* __restrict__ apbits, int* __restrict__ anbits) {
    __shared__ __attribute__((aligned(16))) short sA[128 * 64];
    __shared__ __attribute__((aligned(16))) short sB[128 * 64];

    const int tid  = threadIdx.x;
    const int lane = tid & 63;
    const int wid  = tid >> 6;
    const int wr   = (wid >> 1) * 64;      // wave row offset in 128-tile
    const int wc   = (wid & 1) * 64;       // wave col offset
    const int l15  = lane & 15;
    const int kq   = (lane >> 4) * 8;      // k sub-offset within 32-chunk
    const int swz  = (lane & 7) << 3;      // ushort-index XOR swizzle ((row&7)<<4 bytes)

    const int rowBase = blockIdx.x * 128;
    const int colBase = blockIdx.y * 128;

    f32x4 acc[4][4] = {};

    #pragma unroll
    for (int pass = 0; pass < 3; ++pass) {
        const ushort* Ag = (pass == 2) ? lo : hi;   // hh, hl, lh
        const ushort* Bg = (pass == 1) ? lo : hi;
        for (int kt = 0; kt < D; kt += 64) {
            // stage 128x64 bf16 A and B tiles; LDS linear, global src pre-swizzled
            #pragma unroll
            for (int i = 0; i < 4; ++i) {
                int c   = i * 256 + tid;          // 16B chunk index
                int row = c >> 3;
                int kc  = ((c ^ row) & 7) * 8;    // logical k-chunk (XOR involution)
                __builtin_amdgcn_global_load_lds(
                    (g1_t*)(Ag + (size_t)(rowBase + row) * D + kt + kc),
                    (l3_t*)(sA + c * 8), 16, 0, 0);
                __builtin_amdgcn_global_load_lds(
                    (g1_t*)(Bg + (size_t)(colBase + row) * D + kt + kc),
                    (l3_t*)(sB + c * 8), 16, 0, 0);
            }
            __syncthreads();
            #pragma unroll
            for (int h = 0; h < 2; ++h) {
                short8 af[4], bfv[4];
                #pragma unroll
                for (int m = 0; m < 4; ++m) {
                    int idx = ((wr + m * 16 + l15) << 6) + h * 32 + kq;
                    af[m] = *(const short8*)(sA + (idx ^ swz));
                }
                #pragma unroll
                for (int n = 0; n < 4; ++n) {
                    int idx = ((wc + n * 16 + l15) << 6) + h * 32 + kq;
                    bfv[n] = *(const short8*)(sB + (idx ^ swz));
                }
                #pragma unroll
                for (int m = 0; m < 4; ++m)
                    #pragma unroll
                    for (int n = 0; n < 4; ++n)
                        acc[m][n] = __builtin_amdgcn_mfma_f32_16x16x32_bf16(
                            af[m], bfv[n], acc[m][n], 0, 0, 0);
            }
            __syncthreads();
        }
    }

    // Epilogue: d2 = xr + xc - 2*dot, masked max/min per row, in d^2 domain.
    float xr[4][4]; int lrow[4][4];
    #pragma unroll
    for (int m = 0; m < 4; ++m)
        #pragma unroll
        for (int j = 0; j < 4; ++j) {
            int rg = rowBase + wr + m * 16 + (lane >> 4) * 4 + j;
            xr[m][j] = xx[rg]; lrow[m][j] = labels[rg];
        }
    float xc[4]; int lcol[4];
    #pragma unroll
    for (int n = 0; n < 4; ++n) {
        int cg = colBase + wc + n * 16 + l15;
        xc[n] = xx[cg]; lcol[n] = labels[cg];
    }
    float pm2[4][4], nm2[4][4];
    #pragma unroll
    for (int m = 0; m < 4; ++m)
        #pragma unroll
        for (int j = 0; j < 4; ++j) { pm2[m][j] = 0.0f; nm2[m][j] = 3.402823466e+38f; }

    #pragma unroll
    for (int m = 0; m < 4; ++m)
        #pragma unroll
        for (int n = 0; n < 4; ++n)
            #pragma unroll
            for (int j = 0; j < 4; ++j) {
                float d2 = fmaxf(xr[m][j] + xc[n] - 2.0f * acc[m][n][j], 0.0f);
                bool pos = (lrow[m][j] == lcol[n]);
                pm2[m][j] = pos ? fmaxf(pm2[m][j], d2) : pm2[m][j];
                nm2[m][j] = pos ? nm2[m][j] : fminf(nm2[m][j], d2);
            }

    // reduce over the 16 column-lanes (lane bits 0..3)
    #pragma unroll
    for (int m = 0; m < 4; ++m)
        #pragma unroll
        for (int j = 0; j < 4; ++j) {
            #pragma unroll
            for (int off = 1; off <= 8; off <<= 1) {
                pm2[m][j] = fmaxf(pm2[m][j], __shfl_xor(pm2[m][j], off));
                nm2[m][j] = fminf(nm2[m][j], __shfl_xor(nm2[m][j], off));
            }
        }
    if (l15 == 0) {
        #pragma unroll
        for (int m = 0; m < 4; ++m)
            #pragma unroll
            for (int j = 0; j < 4; ++j) {
                int rg = rowBase + wr + m * 16 + (lane >> 4) * 4 + j;
                atomicMax(apbits + rg, __float_as_int(pm2[m][j]));  // nonneg -> int order ok
                atomicMin(anbits + rg, __float_as_int(nm2[m][j]));
            }
    }
}

// Kernel 3: final margin-ranking loss reduction (single block), sqrt here.
__global__ __launch_bounds__(256) void loss_kernel(
        const int* __restrict__ apbits,
        const int* __restrict__ anbits,
        float* __restrict__ out) {
    __shared__ float ssum[4], scnt[4];
    int tid = threadIdx.x;
    float sum = 0.0f, cnt = 0.0f;
    for (int i = tid; i < N; i += 256) {
        float ap = sqrtf(fmaxf(__int_as_float(apbits[i]), 1e-12f));
        float an = sqrtf(fmaxf(__int_as_float(anbits[i]), 1e-12f));
        bool valid = (ap < 1.0e6f) && (an > 0.0f);
        float per = fmaxf(MARGIN + ap - an, 0.0f);
        if (valid) { sum += per; cnt += 1.0f; }
    }
    #pragma unroll
    for (int off = 32; off >= 1; off >>= 1) {
        sum += __shfl_xor(sum, off);
        cnt += __shfl_xor(cnt, off);
    }
    int wv = tid >> 6;
    if ((tid & 63) == 0) { ssum[wv] = sum; scnt[wv] = cnt; }
    __syncthreads();
    if (tid == 0) {
        float S = ssum[0] + ssum[1] + ssum[2] + ssum[3];
        float C = scnt[0] + scnt[1] + scnt[2] + scnt[3];
        out[0] = (C > 0.0f) ? S / fmaxf(C, 1.0f) : 0.0f;
    }
}

extern "C" void kernel_launch(void* const* d_in, const int* in_sizes, int n_in,
                              void* d_out, int out_size, void* d_ws, size_t ws_size,
                              hipStream_t stream) {
    const float* feat = (const float*)d_in[0];
    const int* labels = (const int*)d_in[1];
    float* xx   = (float*)d_ws;
    int* apbits = (int*)((char*)d_ws + 16384);
    int* anbits = (int*)((char*)d_ws + 32768);
    ushort* hi  = (ushort*)((char*)d_ws + 49152);
    ushort* lo  = (ushort*)((char*)d_ws + 49152 + (size_t)N * D * 2);
    float* out  = (float*)d_out;

    prep_kernel<<<N / 4, 256, 0, stream>>>(feat, xx, apbits, anbits, hi, lo);
    dim3 grid(N / 128, N / 128);
    dist_mfma_kernel<<<grid, 256, 0, stream>>>(hi, lo, labels, xx, apbits, anbits);
    loss_kernel<<<1, 256, 0, stream>>>(apbits, anbits, out);
}

// Round 3
// 33.645 us; speedup vs baseline: 4.3112x; 1.5880x over previous
//
#include <hip/hip_runtime.h>
#include <hip/hip_bf16.h>

#define N 4096
#define D 256
#define MARGIN 0.3f
#define FLT_MAX_BITS 0x7F7FFFFF

typedef __attribute__((ext_vector_type(8))) short short8;
typedef __attribute__((ext_vector_type(4))) float f32x4;
typedef const __attribute__((address_space(1))) unsigned char g1_t;
typedef __attribute__((address_space(3))) unsigned char l3_t;

__device__ __forceinline__ ushort f2bf(float f) {
    unsigned u = __float_as_uint(f);
    unsigned r = (u + 0x7fffu + ((u >> 16) & 1u)) >> 16;   // RNE
    return (ushort)r;
}

// Kernel 1: per-row squared norms (fp32, exact), bf16 cast, init atomic targets.
__global__ __launch_bounds__(256) void prep_kernel(
        const float* __restrict__ feat,
        float* __restrict__ xx,
        int* __restrict__ apbits,
        int* __restrict__ anbits,
        ushort* __restrict__ hi) {
    int row  = blockIdx.x * 4 + (threadIdx.x >> 6);
    int lane = threadIdx.x & 63;
    float4 v = *(const float4*)(feat + row * D + lane * 4);
    *(ushort4*)(hi + row * D + lane * 4) =
        make_ushort4(f2bf(v.x), f2bf(v.y), f2bf(v.z), f2bf(v.w));
    float s = v.x * v.x + v.y * v.y + v.z * v.z + v.w * v.w;
    #pragma unroll
    for (int off = 32; off >= 1; off >>= 1) s += __shfl_xor(s, off);
    if (lane == 0) {
        xx[row]     = s;
        apbits[row] = 0;             // running max of pos d^2 (>= 0)
        anbits[row] = FLT_MAX_BITS;  // running min of neg d^2
    }
}

// Kernel 2: triangular 128x128 bf16-MFMA tiles. For block (bi,bj), bj>=bi,
// compute masked row max/min AND column max/min (the transposed block's rows).
// Max/min merges are idempotent -> diagonal blocks doing both is safe.
__global__ __launch_bounds__(256, 2) void dist_mfma_kernel(
        const ushort* __restrict__ hi,
        const int* __restrict__ labels, const float* __restrict__ xx,
        int* __restrict__ apbits, int* __restrict__ anbits) {
    __shared__ __attribute__((aligned(16))) short sA[128 * 64];
    __shared__ __attribute__((aligned(16))) short sB[128 * 64];

    // triangular decode: blockIdx.x -> (bi, bj) with bj >= bi
    int t = blockIdx.x, bi = 0, rem = 32;
    while (t >= rem) { t -= rem; ++bi; --rem; }
    const int bj = bi + t;
    const int rowBase = bi * 128;
    const int colBase = bj * 128;

    const int tid  = threadIdx.x;
    const int lane = tid & 63;
    const int wid  = tid >> 6;
    const int wr   = (wid >> 1) * 64;      // wave row offset in 128-tile
    const int wc   = (wid & 1) * 64;       // wave col offset
    const int l15  = lane & 15;
    const int kq   = (lane >> 4) * 8;      // k sub-offset within 32-chunk
    const int swz  = (lane & 7) << 3;      // ushort-index XOR swizzle

    f32x4 acc[4][4] = {};

    for (int kt = 0; kt < D; kt += 64) {
        #pragma unroll
        for (int i = 0; i < 4; ++i) {
            int c   = i * 256 + tid;          // 16B chunk index
            int row = c >> 3;
            int kc  = ((c ^ row) & 7) * 8;    // logical k-chunk (XOR involution)
            __builtin_amdgcn_global_load_lds(
                (g1_t*)(hi + (size_t)(rowBase + row) * D + kt + kc),
                (l3_t*)(sA + c * 8), 16, 0, 0);
            __builtin_amdgcn_global_load_lds(
                (g1_t*)(hi + (size_t)(colBase + row) * D + kt + kc),
                (l3_t*)(sB + c * 8), 16, 0, 0);
        }
        __syncthreads();
        #pragma unroll
        for (int h = 0; h < 2; ++h) {
            short8 af[4], bfv[4];
            #pragma unroll
            for (int m = 0; m < 4; ++m) {
                int idx = ((wr + m * 16 + l15) << 6) + h * 32 + kq;
                af[m] = *(const short8*)(sA + (idx ^ swz));
            }
            #pragma unroll
            for (int n = 0; n < 4; ++n) {
                int idx = ((wc + n * 16 + l15) << 6) + h * 32 + kq;
                bfv[n] = *(const short8*)(sB + (idx ^ swz));
            }
            #pragma unroll
            for (int m = 0; m < 4; ++m)
                #pragma unroll
                for (int n = 0; n < 4; ++n)
                    acc[m][n] = __builtin_amdgcn_mfma_f32_16x16x32_bf16(
                        af[m], bfv[n], acc[m][n], 0, 0, 0);
        }
        __syncthreads();
    }

    // Epilogue in d^2 domain (sqrt deferred; monotone).
    float xr[4][4]; int lrow[4][4];
    #pragma unroll
    for (int m = 0; m < 4; ++m)
        #pragma unroll
        for (int j = 0; j < 4; ++j) {
            int rg = rowBase + wr + m * 16 + (lane >> 4) * 4 + j;
            xr[m][j] = xx[rg]; lrow[m][j] = labels[rg];
        }
    float xc[4]; int lcol[4];
    #pragma unroll
    for (int n = 0; n < 4; ++n) {
        int cg = colBase + wc + n * 16 + l15;
        xc[n] = xx[cg]; lcol[n] = labels[cg];
    }

    float pm2[4][4], nm2[4][4];   // row-wise
    float cpm[4],   cnm[4];       // col-wise
    #pragma unroll
    for (int m = 0; m < 4; ++m)
        #pragma unroll
        for (int j = 0; j < 4; ++j) { pm2[m][j] = 0.0f; nm2[m][j] = 3.402823466e+38f; }
    #pragma unroll
    for (int n = 0; n < 4; ++n) { cpm[n] = 0.0f; cnm[n] = 3.402823466e+38f; }

    #pragma unroll
    for (int m = 0; m < 4; ++m)
        #pragma unroll
        for (int n = 0; n < 4; ++n)
            #pragma unroll
            for (int j = 0; j < 4; ++j) {
                float d2 = fmaxf(xr[m][j] + xc[n] - 2.0f * acc[m][n][j], 0.0f);
                bool pos = (lrow[m][j] == lcol[n]);
                if (pos) {
                    pm2[m][j] = fmaxf(pm2[m][j], d2);
                    cpm[n]    = fmaxf(cpm[n],    d2);
                } else {
                    nm2[m][j] = fminf(nm2[m][j], d2);
                    cnm[n]    = fminf(cnm[n],    d2);
                }
            }

    // row-wise: reduce over the 16 column-lanes (lane bits 0..3)
    #pragma unroll
    for (int m = 0; m < 4; ++m)
        #pragma unroll
        for (int j = 0; j < 4; ++j) {
            #pragma unroll
            for (int off = 1; off <= 8; off <<= 1) {
                pm2[m][j] = fmaxf(pm2[m][j], __shfl_xor(pm2[m][j], off));
                nm2[m][j] = fminf(nm2[m][j], __shfl_xor(nm2[m][j], off));
            }
        }
    if (l15 == 0) {
        #pragma unroll
        for (int m = 0; m < 4; ++m)
            #pragma unroll
            for (int j = 0; j < 4; ++j) {
                int rg = rowBase + wr + m * 16 + (lane >> 4) * 4 + j;
                atomicMax(apbits + rg, __float_as_int(pm2[m][j]));
                atomicMin(anbits + rg, __float_as_int(nm2[m][j]));
            }
    }

    // col-wise: reduce over the 4 row-lane-groups (lane bits 4..5)
    #pragma unroll
    for (int n = 0; n < 4; ++n) {
        #pragma unroll
        for (int off = 16; off <= 32; off <<= 1) {
            cpm[n] = fmaxf(cpm[n], __shfl_xor(cpm[n], off));
            cnm[n] = fminf(cnm[n], __shfl_xor(cnm[n], off));
        }
    }
    if (lane < 16) {
        #pragma unroll
        for (int n = 0; n < 4; ++n) {
            int cg = colBase + wc + n * 16 + l15;
            atomicMax(apbits + cg, __float_as_int(cpm[n]));
            atomicMin(anbits + cg, __float_as_int(cnm[n]));
        }
    }
}

// Kernel 3: final margin-ranking loss reduction (single block), sqrt here.
__global__ __launch_bounds__(256) void loss_kernel(
        const int* __restrict__ apbits,
        const int* __restrict__ anbits,
        float* __restrict__ out) {
    __shared__ float ssum[4], scnt[4];
    int tid = threadIdx.x;
    float sum = 0.0f, cnt = 0.0f;
    for (int i = tid; i < N; i += 256) {
        float ap = sqrtf(fmaxf(__int_as_float(apbits[i]), 1e-12f));
        float an = sqrtf(fmaxf(__int_as_float(anbits[i]), 1e-12f));
        bool valid = (ap < 1.0e6f) && (an > 0.0f);
        float per = fmaxf(MARGIN + ap - an, 0.0f);
        if (valid) { sum += per; cnt += 1.0f; }
    }
    #pragma unroll
    for (int off = 32; off >= 1; off >>= 1) {
        sum += __shfl_xor(sum, off);
        cnt += __shfl_xor(cnt, off);
    }
    int wv = tid >> 6;
    if ((tid & 63) == 0) { ssum[wv] = sum; scnt[wv] = cnt; }
    __syncthreads();
    if (tid == 0) {
        float S = ssum[0] + ssum[1] + ssum[2] + ssum[3];
        float C = scnt[0] + scnt[1] + scnt[2] + scnt[3];
        out[0] = (C > 0.0f) ? S / fmaxf(C, 1.0f) : 0.0f;
    }
}

extern "C" void kernel_launch(void* const* d_in, const int* in_sizes, int n_in,
                              void* d_out, int out_size, void* d_ws, size_t ws_size,
                              hipStream_t stream) {
    const float* feat = (const float*)d_in[0];
    const int* labels = (const int*)d_in[1];
    float* xx   = (float*)d_ws;
    int* apbits = (int*)((char*)d_ws + 16384);
    int* anbits = (int*)((char*)d_ws + 32768);
    ushort* hi  = (ushort*)((char*)d_ws + 49152);
    float* out  = (float*)d_out;

    prep_kernel<<<N / 4, 256, 0, stream>>>(feat, xx, apbits, anbits, hi);
    dist_mfma_kernel<<<528, 256, 0, stream>>>(hi, labels, xx, apbits, anbits);
    loss_kernel<<<1, 256, 0, stream>>>(apbits, anbits, out);
}